// Round 1
// baseline (823.426 us; speedup 1.0000x reference)
//
#include <hip/hip_runtime.h>
#include <hip/hip_fp16.h>
#include <math.h>

#define N_NODES 50000
#define IN_F 256
#define OUT_F 64
#define NBUCK 391   // ceil(50000/128): buckets of 128 destination rows
#define CHUNK 4096  // edges per bin block
#define CAPB 4608   // fixed bucket capacity: mean 4096 + 8 sigma (sigma=64)

typedef unsigned int uint;

// ---------------------------------------------------------------------------
// 3-kernel pipeline:
//   gemm:   support = feat @ W (fp32 compute), stored FP16; zeroes gcnt
//   bin:    single-pass bucket binning. LDS stage + 391-bucket hist, one
//           global atomicAdd per (block,bucket) to claim a base, scatter
//           packed (row7|col16, w) into fixed-stride bucket regions.
//   reduce: one block per bucket: 128x64 fp32 accumulator in LDS,
//           full wave per edge (lane = column), ds_add_f32 accumulate
//           (conflict-free: r*64+lane -> 2 lanes/bank), fused tanh + f4 store.
// ---------------------------------------------------------------------------

// ---- tiled dense projection: support(FP16) = features @ W ----
__global__ __launch_bounds__(256) void gemm_kernel(const float* __restrict__ feat,
                                                   const float* __restrict__ W,
                                                   __half* __restrict__ sup,
                                                   int* __restrict__ gcnt) {
    // stream-ordered init of bucket counters (visible to bin_kernel)
    if (blockIdx.x == 0) {
        for (int i = threadIdx.x; i < NBUCK; i += 256) gcnt[i] = 0;
    }

    __shared__ float A_s[128 * 18];
    __shared__ float B_s[16 * 64];

    const int t = threadIdx.x;
    const int row0 = blockIdx.x * 128;
    const int tc = t & 15;
    const int tr = t >> 4;
    const int ar = t >> 2;
    const int ac = t & 3;

    int gr0 = row0 + ar;      if (gr0 >= N_NODES) gr0 = N_NODES - 1;
    int gr1 = row0 + ar + 64; if (gr1 >= N_NODES) gr1 = N_NODES - 1;
    const float4* gA0 = (const float4*)(feat + (size_t)gr0 * IN_F);
    const float4* gA1 = (const float4*)(feat + (size_t)gr1 * IN_F);
    const float4* gB  = (const float4*)W;

    float acc[8][4];
#pragma unroll
    for (int r = 0; r < 8; ++r)
#pragma unroll
        for (int i = 0; i < 4; ++i) acc[r][i] = 0.f;

    float4 a0 = gA0[ac];
    float4 a1 = gA1[ac];
    float4 bb = gB[(t >> 4) * 16 + tc];

    for (int ch = 0; ch < 16; ++ch) {
        {
            float* ap0 = &A_s[ar * 18 + ac * 4];
            ap0[0] = a0.x; ap0[1] = a0.y; ap0[2] = a0.z; ap0[3] = a0.w;
            float* ap1 = &A_s[(ar + 64) * 18 + ac * 4];
            ap1[0] = a1.x; ap1[1] = a1.y; ap1[2] = a1.z; ap1[3] = a1.w;
            *(float4*)&B_s[(t >> 4) * 64 + tc * 4] = bb;
        }
        __syncthreads();

        if (ch < 15) {
            a0 = gA0[(ch + 1) * 4 + ac];
            a1 = gA1[(ch + 1) * 4 + ac];
            bb = gB[((ch + 1) * 16 + (t >> 4)) * 16 + tc];
        }

#pragma unroll
        for (int k = 0; k < 16; ++k) {
            float b0 = B_s[k * 64 + tc * 4 + 0];
            float b1 = B_s[k * 64 + tc * 4 + 1];
            float b2 = B_s[k * 64 + tc * 4 + 2];
            float b3 = B_s[k * 64 + tc * 4 + 3];
#pragma unroll
            for (int r = 0; r < 8; ++r) {
                float av = A_s[(tr * 8 + r) * 18 + k];
                acc[r][0] += av * b0;
                acc[r][1] += av * b1;
                acc[r][2] += av * b2;
                acc[r][3] += av * b3;
            }
        }
        __syncthreads();
    }

#pragma unroll
    for (int r = 0; r < 8; ++r) {
        int row = row0 + tr * 8 + r;
        if (row < N_NODES) {
            __half2 h01 = __floats2half2_rn(acc[r][0], acc[r][1]);
            __half2 h23 = __floats2half2_rn(acc[r][2], acc[r][3]);
            uint2 u;
            u.x = *(unsigned int*)&h01;
            u.y = *(unsigned int*)&h23;
            *(uint2*)&sup[(size_t)row * OUT_F + tc * 4] = u;
        }
    }
}

// ---- single-pass bucket binning ----
__global__ __launch_bounds__(1024) void bin_kernel(const int* __restrict__ erow,
                                                   const int* __restrict__ ecol,
                                                   const float* __restrict__ ew,
                                                   int* __restrict__ gcnt,
                                                   int2* __restrict__ ecw, int E) {
    __shared__ int   h[NBUCK];      // hist -> absolute cursor
    __shared__ uint  pkst[CHUNK];   // (row<<16)|col   16 KB
    __shared__ float wst[CHUNK];    // edge weight     16 KB
    const int t = threadIdx.x;
    const int base = blockIdx.x * CHUNK;

    for (int i = t; i < NBUCK; i += 1024) h[i] = 0;
    __syncthreads();

    const int e4 = base + 4 * t;
    if (e4 + 3 < E) {
        int4   r4 = *(const int4*)(erow + e4);
        int4   c4 = *(const int4*)(ecol + e4);
        float4 w4 = *(const float4*)(ew + e4);
        pkst[4 * t + 0] = ((uint)r4.x << 16) | (uint)c4.x;
        pkst[4 * t + 1] = ((uint)r4.y << 16) | (uint)c4.y;
        pkst[4 * t + 2] = ((uint)r4.z << 16) | (uint)c4.z;
        pkst[4 * t + 3] = ((uint)r4.w << 16) | (uint)c4.w;
        *(float4*)(wst + 4 * t) = w4;
        atomicAdd(&h[r4.x >> 7], 1);
        atomicAdd(&h[r4.y >> 7], 1);
        atomicAdd(&h[r4.z >> 7], 1);
        atomicAdd(&h[r4.w >> 7], 1);
    } else {
        for (int k = 0; k < 4; ++k) {
            int e = e4 + k;
            if (e < E) {
                int row = erow[e];
                pkst[4 * t + k] = ((uint)row << 16) | (uint)ecol[e];
                wst[4 * t + k] = ew[e];
                atomicAdd(&h[row >> 7], 1);
            }
        }
    }
    __syncthreads();

    // claim global base per bucket (one device atomic per non-empty bucket)
    for (int i = t; i < NBUCK; i += 1024) {
        int c = h[i];
        if (c > 0) h[i] = atomicAdd(&gcnt[i], c);
    }
    __syncthreads();

    const int lim = min(CHUNK, E - base);
    for (int i = t; i < lim; i += 1024) {
        uint  pk = pkst[i];
        float w  = wst[i];
        int b = (int)(pk >> 23);               // row >> 7
        int pos = atomicAdd(&h[b], 1);         // absolute position in bucket
        if (pos < CAPB)
            ecw[(size_t)b * CAPB + pos] =
                make_int2((int)(pk & 0x7FFFFF), __float_as_int(w));
    }
}

// ---- bucket reduce: LDS fp32 accumulate + fused tanh ----
__global__ __launch_bounds__(1024) void reduce_kernel(const __half* __restrict__ sup,
                                                      const int* __restrict__ gcnt,
                                                      const int2* __restrict__ ecw,
                                                      const int* __restrict__ active,
                                                      float* __restrict__ out) {
    __shared__ float acc[128 * 64];  // 32 KB; addr r*64+lane -> 2 lanes/bank (free)
    const int t = threadIdx.x;
    const int b = blockIdx.x;

    for (int i = t; i < 2048; i += 1024)
        ((float4*)acc)[i] = make_float4(0.f, 0.f, 0.f, 0.f);
    __syncthreads();

    int n = gcnt[b]; if (n > CAPB) n = CAPB;
    const int2* eptr = ecw + (size_t)b * CAPB;
    const int wid  = t >> 6;
    const int lane = t & 63;

    // full wave per edge: lane = output column; 4-edge unroll for MLP
    for (int j0 = 4 * wid; j0 < n; j0 += 64) {
        if (j0 + 4 <= n) {
            int2 p0 = eptr[j0], p1 = eptr[j0 + 1], p2 = eptr[j0 + 2], p3 = eptr[j0 + 3];
            uint x0 = (uint)__builtin_amdgcn_readfirstlane(p0.x);
            uint x1 = (uint)__builtin_amdgcn_readfirstlane(p1.x);
            uint x2 = (uint)__builtin_amdgcn_readfirstlane(p2.x);
            uint x3 = (uint)__builtin_amdgcn_readfirstlane(p3.x);
            float w0 = __int_as_float(__builtin_amdgcn_readfirstlane(p0.y));
            float w1 = __int_as_float(__builtin_amdgcn_readfirstlane(p1.y));
            float w2 = __int_as_float(__builtin_amdgcn_readfirstlane(p2.y));
            float w3 = __int_as_float(__builtin_amdgcn_readfirstlane(p3.y));
            float v0 = __half2float(sup[((size_t)(x0 & 0xFFFF) << 6) + lane]);
            float v1 = __half2float(sup[((size_t)(x1 & 0xFFFF) << 6) + lane]);
            float v2 = __half2float(sup[((size_t)(x2 & 0xFFFF) << 6) + lane]);
            float v3 = __half2float(sup[((size_t)(x3 & 0xFFFF) << 6) + lane]);
            atomicAdd(&acc[((x0 >> 16) & 127) * 64 + lane], w0 * v0);
            atomicAdd(&acc[((x1 >> 16) & 127) * 64 + lane], w1 * v1);
            atomicAdd(&acc[((x2 >> 16) & 127) * 64 + lane], w2 * v2);
            atomicAdd(&acc[((x3 >> 16) & 127) * 64 + lane], w3 * v3);
        } else {
            for (int q = 0; q < 4; ++q) {
                int j = j0 + q;
                if (j < n) {
                    int2 p = eptr[j];
                    uint  x = (uint)__builtin_amdgcn_readfirstlane(p.x);
                    float w = __int_as_float(__builtin_amdgcn_readfirstlane(p.y));
                    float v = __half2float(sup[((size_t)(x & 0xFFFF) << 6) + lane]);
                    atomicAdd(&acc[((x >> 16) & 127) * 64 + lane], w * v);
                }
            }
        }
    }
    __syncthreads();

    const int act = *active;
    for (int i = t; i < 2048; i += 1024) {
        int r = i >> 4, c4 = i & 15;
        int row = b * 128 + r;
        if (row < N_NODES) {
            float4 v = ((float4*)acc)[i];
            if (act) { v.x = tanhf(v.x); v.y = tanhf(v.y); v.z = tanhf(v.z); v.w = tanhf(v.w); }
            *(float4*)&out[(size_t)row * OUT_F + 4 * c4] = v;
        }
    }
}

extern "C" void kernel_launch(void* const* d_in, const int* in_sizes, int n_in,
                              void* d_out, int out_size, void* d_ws, size_t ws_size,
                              hipStream_t stream) {
    const float* feat = (const float*)d_in[0];
    const float* W    = (const float*)d_in[1];
    const int*   erow = (const int*)d_in[2];
    const int*   ecol = (const int*)d_in[3];
    const float* ew   = (const float*)d_in[4];
    const int*   act  = (const int*)d_in[5];
    float* out = (float*)d_out;

    const int E = in_sizes[2];
    const int G = (E + CHUNK - 1) / CHUNK;

    // workspace carve-up (8B-aligned segments)
    char* ws = (char*)d_ws;
    __half* sup  = (__half*)ws; ws += (size_t)N_NODES * OUT_F * 2;   // 6.4 MB
    int2*   ecw  = (int2*)ws;   ws += (size_t)NBUCK * CAPB * 8;      // 14.4 MB
    int*    gcnt = (int*)ws;                                         // 1.6 KB

    gemm_kernel<<<(N_NODES + 127) / 128, 256, 0, stream>>>(feat, W, sup, gcnt);
    bin_kernel<<<G, 1024, 0, stream>>>(erow, ecol, ew, gcnt, ecw, E);
    reduce_kernel<<<NBUCK, 1024, 0, stream>>>(sup, gcnt, ecw, act, out);
}

// Round 2
// 180.832 us; speedup vs baseline: 4.5535x; 4.5535x over previous
//
#include <hip/hip_runtime.h>
#include <hip/hip_fp16.h>
#include <math.h>

#define N_NODES 50000
#define IN_F 256
#define OUT_F 64
#define NBUCK 391   // ceil(50000/128): buckets of 128 destination rows
#define CHUNK 4096  // edges per bin block
#define CAPB 4608   // fixed bucket capacity: mean 4096 + 8 sigma (sigma=64)

typedef unsigned int uint;

// ---------------------------------------------------------------------------
// 3-kernel pipeline (NO fp atomics anywhere -- fp32 LDS atomicAdd is a CAS
// loop on gfx950 and cost 688us in the previous round):
//   gemm:   support = feat @ W (fp32 compute), stored FP16; zeroes gcnt
//   bin:    single-pass bucket binning. LDS stage + 391-bucket int hist, one
//           global atomicAdd per (block,bucket) to claim a base, scatter
//           packed (row7|col16, w) into fixed-stride bucket regions.
//   reduce: one block per bucket: stage edges in LDS, 128-bin int hist+scan,
//           LDS re-rank to row-sorted order (all int atomics, native ds_add),
//           then half-wave-per-edge register reduce (round-0's proven inner
//           loop, metadata from LDS), fused tanh + float2 store.
// ---------------------------------------------------------------------------

// ---- tiled dense projection: support(FP16) = features @ W ----
__global__ __launch_bounds__(256) void gemm_kernel(const float* __restrict__ feat,
                                                   const float* __restrict__ W,
                                                   __half* __restrict__ sup,
                                                   int* __restrict__ gcnt) {
    // stream-ordered init of bucket counters (visible to bin_kernel)
    if (blockIdx.x == 0) {
        for (int i = threadIdx.x; i < NBUCK; i += 256) gcnt[i] = 0;
    }

    __shared__ float A_s[128 * 18];
    __shared__ float B_s[16 * 64];

    const int t = threadIdx.x;
    const int row0 = blockIdx.x * 128;
    const int tc = t & 15;
    const int tr = t >> 4;
    const int ar = t >> 2;
    const int ac = t & 3;

    int gr0 = row0 + ar;      if (gr0 >= N_NODES) gr0 = N_NODES - 1;
    int gr1 = row0 + ar + 64; if (gr1 >= N_NODES) gr1 = N_NODES - 1;
    const float4* gA0 = (const float4*)(feat + (size_t)gr0 * IN_F);
    const float4* gA1 = (const float4*)(feat + (size_t)gr1 * IN_F);
    const float4* gB  = (const float4*)W;

    float acc[8][4];
#pragma unroll
    for (int r = 0; r < 8; ++r)
#pragma unroll
        for (int i = 0; i < 4; ++i) acc[r][i] = 0.f;

    float4 a0 = gA0[ac];
    float4 a1 = gA1[ac];
    float4 bb = gB[(t >> 4) * 16 + tc];

    for (int ch = 0; ch < 16; ++ch) {
        {
            float* ap0 = &A_s[ar * 18 + ac * 4];
            ap0[0] = a0.x; ap0[1] = a0.y; ap0[2] = a0.z; ap0[3] = a0.w;
            float* ap1 = &A_s[(ar + 64) * 18 + ac * 4];
            ap1[0] = a1.x; ap1[1] = a1.y; ap1[2] = a1.z; ap1[3] = a1.w;
            *(float4*)&B_s[(t >> 4) * 64 + tc * 4] = bb;
        }
        __syncthreads();

        if (ch < 15) {
            a0 = gA0[(ch + 1) * 4 + ac];
            a1 = gA1[(ch + 1) * 4 + ac];
            bb = gB[((ch + 1) * 16 + (t >> 4)) * 16 + tc];
        }

#pragma unroll
        for (int k = 0; k < 16; ++k) {
            float b0 = B_s[k * 64 + tc * 4 + 0];
            float b1 = B_s[k * 64 + tc * 4 + 1];
            float b2 = B_s[k * 64 + tc * 4 + 2];
            float b3 = B_s[k * 64 + tc * 4 + 3];
#pragma unroll
            for (int r = 0; r < 8; ++r) {
                float av = A_s[(tr * 8 + r) * 18 + k];
                acc[r][0] += av * b0;
                acc[r][1] += av * b1;
                acc[r][2] += av * b2;
                acc[r][3] += av * b3;
            }
        }
        __syncthreads();
    }

#pragma unroll
    for (int r = 0; r < 8; ++r) {
        int row = row0 + tr * 8 + r;
        if (row < N_NODES) {
            __half2 h01 = __floats2half2_rn(acc[r][0], acc[r][1]);
            __half2 h23 = __floats2half2_rn(acc[r][2], acc[r][3]);
            uint2 u;
            u.x = *(unsigned int*)&h01;
            u.y = *(unsigned int*)&h23;
            *(uint2*)&sup[(size_t)row * OUT_F + tc * 4] = u;
        }
    }
}

// ---- single-pass bucket binning (int LDS atomics only) ----
__global__ __launch_bounds__(1024) void bin_kernel(const int* __restrict__ erow,
                                                   const int* __restrict__ ecol,
                                                   const float* __restrict__ ew,
                                                   int* __restrict__ gcnt,
                                                   int2* __restrict__ ecw, int E) {
    __shared__ int   h[NBUCK];      // hist -> absolute cursor
    __shared__ uint  pkst[CHUNK];   // (row<<16)|col   16 KB
    __shared__ float wst[CHUNK];    // edge weight     16 KB
    const int t = threadIdx.x;
    const int base = blockIdx.x * CHUNK;

    for (int i = t; i < NBUCK; i += 1024) h[i] = 0;
    __syncthreads();

    const int e4 = base + 4 * t;
    if (e4 + 3 < E) {
        int4   r4 = *(const int4*)(erow + e4);
        int4   c4 = *(const int4*)(ecol + e4);
        float4 w4 = *(const float4*)(ew + e4);
        pkst[4 * t + 0] = ((uint)r4.x << 16) | (uint)c4.x;
        pkst[4 * t + 1] = ((uint)r4.y << 16) | (uint)c4.y;
        pkst[4 * t + 2] = ((uint)r4.z << 16) | (uint)c4.z;
        pkst[4 * t + 3] = ((uint)r4.w << 16) | (uint)c4.w;
        *(float4*)(wst + 4 * t) = w4;
        atomicAdd(&h[r4.x >> 7], 1);
        atomicAdd(&h[r4.y >> 7], 1);
        atomicAdd(&h[r4.z >> 7], 1);
        atomicAdd(&h[r4.w >> 7], 1);
    } else {
        for (int k = 0; k < 4; ++k) {
            int e = e4 + k;
            if (e < E) {
                int row = erow[e];
                pkst[4 * t + k] = ((uint)row << 16) | (uint)ecol[e];
                wst[4 * t + k] = ew[e];
                atomicAdd(&h[row >> 7], 1);
            }
        }
    }
    __syncthreads();

    // claim global base per bucket (one device atomic per non-empty bucket)
    for (int i = t; i < NBUCK; i += 1024) {
        int c = h[i];
        if (c > 0) h[i] = atomicAdd(&gcnt[i], c);
    }
    __syncthreads();

    const int lim = min(CHUNK, E - base);
    for (int i = t; i < lim; i += 1024) {
        uint  pk = pkst[i];
        float w  = wst[i];
        int b = (int)(pk >> 23);               // row >> 7
        int pos = atomicAdd(&h[b], 1);         // absolute position in bucket
        if (pos < CAPB)
            ecw[(size_t)b * CAPB + pos] =
                make_int2((int)(pk & 0x7FFFFF), __float_as_int(w));
    }
}

// ---- bucket reduce: LDS sort (int atomics) + register accumulate ----
__global__ __launch_bounds__(1024) void reduce_kernel(const __half* __restrict__ sup,
                                                      const int* __restrict__ gcnt,
                                                      const int2* __restrict__ ecw,
                                                      const int* __restrict__ active,
                                                      float* __restrict__ out) {
    __shared__ int2 stA[CAPB];   // raw bucket edges      36.9 KB
    __shared__ int2 stB[CAPB];   // row-sorted edges      36.9 KB
    __shared__ int h[128];
    __shared__ int sc[128];
    __shared__ int cur[128];
    const int t = threadIdx.x;
    const int b = blockIdx.x;

    int n = gcnt[b]; if (n > CAPB) n = CAPB;
    const int2* eptr = ecw + (size_t)b * CAPB;

    if (t < 128) h[t] = 0;
    __syncthreads();

    // stage + 128-row histogram (native ds_add_u32)
    for (int i = t; i < n; i += 1024) {
        int2 d = eptr[i];
        stA[i] = d;
        atomicAdd(&h[(d.x >> 16) & 127], 1);
    }
    __syncthreads();

    // 128-entry inclusive scan
    if (t < 128) sc[t] = h[t];
    __syncthreads();
    for (int off = 1; off < 128; off <<= 1) {
        int u = (t < 128 && t >= off) ? sc[t - off] : 0;
        __syncthreads();
        if (t < 128) sc[t] += u;
        __syncthreads();
    }
    if (t < 128) cur[t] = sc[t] - h[t];
    __syncthreads();

    // scatter to row-sorted order within LDS
    for (int i = t; i < n; i += 1024) {
        int2 d = stA[i];
        int r = (d.x >> 16) & 127;
        int pos = atomicAdd(&cur[r], 1);
        stB[pos] = make_int2(d.x & 0xFFFF, d.y);
    }
    __syncthreads();

    // per-row register reduce: one wave per row (8 rows/wave), half-wave per
    // edge, each lane gathers a half2 (2 cols) from sup, shfl_xor(32) combine.
    const int wid  = t >> 6;
    const int lane = t & 63;
    const int hl   = lane & 31;
    const bool hi  = lane >= 32;
    const int act  = *active;

    for (int r = wid; r < 128; r += 16) {
        int row = b * 128 + r;
        if (row >= N_NODES) break;   // wave-uniform (last bucket tail only)
        const int s = sc[r] - h[r];
        const int e = sc[r];
        float ax = 0.f, ay = 0.f;
        int j = s;
        for (; j + 8 <= e; j += 8) {
#pragma unroll
            for (int q = 0; q < 4; ++q) {
                int2 pa = stB[j + 2 * q];
                int2 pb = stB[j + 2 * q + 1];
                int   col = hi ? pb.x : pa.x;
                float w   = __int_as_float(hi ? pb.y : pa.y);
                const __half2* hp = (const __half2*)(sup + ((size_t)col << 6));
                float2 v = __half22float2(hp[hl]);
                ax += w * v.x;
                ay += w * v.y;
            }
        }
        for (; j + 2 <= e; j += 2) {
            int2 pa = stB[j];
            int2 pb = stB[j + 1];
            int   col = hi ? pb.x : pa.x;
            float w   = __int_as_float(hi ? pb.y : pa.y);
            const __half2* hp = (const __half2*)(sup + ((size_t)col << 6));
            float2 v = __half22float2(hp[hl]);
            ax += w * v.x;
            ay += w * v.y;
        }
        if (j < e) {  // odd tail: hi half contributes zero
            int2 pa = stB[j];
            int   col = pa.x;
            float w   = hi ? 0.f : __int_as_float(pa.y);
            const __half2* hp = (const __half2*)(sup + ((size_t)col << 6));
            float2 v = __half22float2(hp[hl]);
            ax += w * v.x;
            ay += w * v.y;
        }

        ax += __shfl_xor(ax, 32, 64);
        ay += __shfl_xor(ay, 32, 64);

        if (!hi) {
            if (act) { ax = tanhf(ax); ay = tanhf(ay); }
            *(float2*)&out[((size_t)row << 6) + 2 * hl] = make_float2(ax, ay);
        }
    }
}

extern "C" void kernel_launch(void* const* d_in, const int* in_sizes, int n_in,
                              void* d_out, int out_size, void* d_ws, size_t ws_size,
                              hipStream_t stream) {
    const float* feat = (const float*)d_in[0];
    const float* W    = (const float*)d_in[1];
    const int*   erow = (const int*)d_in[2];
    const int*   ecol = (const int*)d_in[3];
    const float* ew   = (const float*)d_in[4];
    const int*   act  = (const int*)d_in[5];
    float* out = (float*)d_out;

    const int E = in_sizes[2];
    const int G = (E + CHUNK - 1) / CHUNK;

    // workspace carve-up (8B-aligned segments)
    char* ws = (char*)d_ws;
    __half* sup  = (__half*)ws; ws += (size_t)N_NODES * OUT_F * 2;   // 6.4 MB
    int2*   ecw  = (int2*)ws;   ws += (size_t)NBUCK * CAPB * 8;      // 14.4 MB
    int*    gcnt = (int*)ws;                                         // 1.6 KB

    gemm_kernel<<<(N_NODES + 127) / 128, 256, 0, stream>>>(feat, W, sup, gcnt);
    bin_kernel<<<G, 1024, 0, stream>>>(erow, ecol, ew, gcnt, ecw, E);
    reduce_kernel<<<NBUCK, 1024, 0, stream>>>(sup, gcnt, ecw, act, out);
}